// Round 14
// baseline (301.641 us; speedup 1.0000x reference)
//
#include <hip/hip_runtime.h>
#include <stdint.h>

typedef __bf16 bf16x8 __attribute__((ext_vector_type(8)));
typedef float  floatx4 __attribute__((ext_vector_type(4)));
typedef float  floatx2 __attribute__((ext_vector_type(2)));
typedef __fp16 h2 __attribute__((ext_vector_type(2)));

__device__ __forceinline__ unsigned short f2b(float x){
    unsigned u = __float_as_uint(x);
    u = u + 0x7FFFu + ((u >> 16) & 1u);          // RNE
    return (unsigned short)(u >> 16);
}
__device__ __forceinline__ float b2f(unsigned short h){
    return __uint_as_float(((unsigned)h) << 16);
}
__device__ __forceinline__ unsigned char f2f8(float x){
    int p = __builtin_amdgcn_cvt_pk_fp8_f32(x, x, 0, false);
    return (unsigned char)(p & 0xff);
}

// accumulate 16 fp8 (uint4) into acc[16]
#define ACC16(v) do{ \
    floatx2 p; \
    p = __builtin_amdgcn_cvt_pk_f32_fp8((int)(v).x, false); acc[0]+=p.x;  acc[1]+=p.y;  \
    p = __builtin_amdgcn_cvt_pk_f32_fp8((int)(v).x, true ); acc[2]+=p.x;  acc[3]+=p.y;  \
    p = __builtin_amdgcn_cvt_pk_f32_fp8((int)(v).y, false); acc[4]+=p.x;  acc[5]+=p.y;  \
    p = __builtin_amdgcn_cvt_pk_f32_fp8((int)(v).y, true ); acc[6]+=p.x;  acc[7]+=p.y;  \
    p = __builtin_amdgcn_cvt_pk_f32_fp8((int)(v).z, false); acc[8]+=p.x;  acc[9]+=p.y;  \
    p = __builtin_amdgcn_cvt_pk_f32_fp8((int)(v).z, true ); acc[10]+=p.x; acc[11]+=p.y; \
    p = __builtin_amdgcn_cvt_pk_f32_fp8((int)(v).w, false); acc[12]+=p.x; acc[13]+=p.y; \
    p = __builtin_amdgcn_cvt_pk_f32_fp8((int)(v).w, true ); acc[14]+=p.x; acc[15]+=p.y; \
}while(0)

// accumulate 8 bf16 (uint4) into acc[8]
#define ACC8(v) do{ \
    acc[0]+=b2f((unsigned short)(v).x); acc[1]+=b2f((unsigned short)((v).x>>16)); \
    acc[2]+=b2f((unsigned short)(v).y); acc[3]+=b2f((unsigned short)((v).y>>16)); \
    acc[4]+=b2f((unsigned short)(v).z); acc[5]+=b2f((unsigned short)((v).z>>16)); \
    acc[6]+=b2f((unsigned short)(v).w); acc[7]+=b2f((unsigned short)((v).w>>16)); \
}while(0)

// ================= CSR build: reservation counting sort (single pass) =========
__global__ __launch_bounds__(256) void k_scatter2(const int* __restrict__ src,
                                                  const int* __restrict__ dst,
                                                  int* __restrict__ gcur,
                                                  unsigned* __restrict__ slab,
                                                  int E_, int nbins){
    __shared__ int h[1024];
    __shared__ unsigned wbuf[4096];
    __shared__ unsigned short bbuf[4096];
    int t = threadIdx.x, blk = blockIdx.x;
    for (int i = t; i < nbins; i += 256) h[i] = 0;
    __syncthreads();
    int base = blk * 4096;
    int valid = E_ - base; if (valid > 4096) valid = 4096;
    #pragma unroll
    for (int j = 0; j < 4; j++){
        int li = (j * 256 + t) * 4;
        int e = base + li;
        if (e < E_){
            int4 d = *(const int4*)(dst + e);
            int4 s = *(const int4*)(src + e);
            wbuf[li + 0] = ((unsigned)(d.x & 127) << 25) | (unsigned)s.x;
            wbuf[li + 1] = ((unsigned)(d.y & 127) << 25) | (unsigned)s.y;
            wbuf[li + 2] = ((unsigned)(d.z & 127) << 25) | (unsigned)s.z;
            wbuf[li + 3] = ((unsigned)(d.w & 127) << 25) | (unsigned)s.w;
            bbuf[li + 0] = (unsigned short)(d.x >> 7);
            bbuf[li + 1] = (unsigned short)(d.y >> 7);
            bbuf[li + 2] = (unsigned short)(d.z >> 7);
            bbuf[li + 3] = (unsigned short)(d.w >> 7);
            atomicAdd(&h[d.x >> 7], 1);
            atomicAdd(&h[d.y >> 7], 1);
            atomicAdd(&h[d.z >> 7], 1);
            atomicAdd(&h[d.w >> 7], 1);
        }
    }
    __syncthreads();
    for (int i = t; i < nbins; i += 256){
        int hv = h[i];
        h[i] = hv ? atomicAdd(&gcur[i], hv) : 0;
    }
    __syncthreads();
    for (int i = t; i < valid; i += 256){
        int bin = bbuf[i];
        int p = atomicAdd(&h[bin], 1);
        slab[(size_t)bin * 4096 + p] = wbuf[i];
    }
}

// one block per bin: prefix from gcur; LDS count/scan/rank; coalesced csr write.
__global__ __launch_bounds__(256) void k_binsort(const unsigned* __restrict__ slab,
                                                 const int* __restrict__ gcur,
                                                 int* __restrict__ csr,
                                                 int* __restrict__ cnt,
                                                 int* __restrict__ off,
                                                 float* __restrict__ dinv,
                                                 int n, int nbins){
    int b = blockIdx.x, t = threadIdx.x;
    __shared__ int sv[1024], sp[256];
    #pragma unroll
    for (int k = 0; k < 4; k++){
        int i = t * 4 + k;
        sv[i] = (i < nbins) ? gcur[i] : 0;
    }
    __syncthreads();
    int a0 = sv[t * 4], a1 = sv[t * 4 + 1], a2 = sv[t * 4 + 2], a3 = sv[t * 4 + 3];
    sp[t] = a0 + a1 + a2 + a3;
    __syncthreads();
    for (int o = 1; o < 256; o <<= 1){
        int v = (t >= o) ? sp[t - o] : 0;
        __syncthreads();
        sp[t] += v;
        __syncthreads();
    }
    int basep = t ? sp[t - 1] : 0;
    sv[t * 4]     = basep;
    sv[t * 4 + 1] = basep + a0;
    sv[t * 4 + 2] = basep + a0 + a1;
    sv[t * 4 + 3] = basep + a0 + a1 + a2;
    __syncthreads();
    int s0 = sv[b];
    int len = gcur[b];
    if (len > 4096) len = 4096;
    const unsigned* seg = slab + (size_t)b * 4096;
    __shared__ int cl[128], sc[128], cur[128];
    __shared__ unsigned buf[4096], outb[4096];
    if (t < 128){ cl[t] = 0; cur[t] = 0; }
    __syncthreads();
    for (int i = t; i < len; i += 256) buf[i] = seg[i];
    __syncthreads();
    for (int i = t; i < len; i += 256) atomicAdd(&cl[buf[i] >> 25], 1);
    __syncthreads();
    if (t < 128) sc[t] = cl[t];
    __syncthreads();
    for (int o = 1; o < 128; o <<= 1){
        int v = 0;
        if (t < 128 && t >= o) v = sc[t - o];
        __syncthreads();
        if (t < 128) sc[t] += v;
        __syncthreads();
    }
    for (int i = t; i < len; i += 256){
        unsigned w = buf[i];
        int nd = (int)(w >> 25);
        int p = (sc[nd] - cl[nd]) + atomicAdd(&cur[nd], 1);
        outb[p] = w & 0x1FFFFFFu;
    }
    __syncthreads();
    for (int i = t; i < len; i += 256) csr[s0 + i] = (int)outb[i];
    if (t < 128){
        int node = b * 128 + t;
        if (node < n){
            cnt[node] = cl[t];
            off[node] = s0 + (sc[t] - cl[t]);
            dinv[node] = rsqrtf((float)cl[t] + 1.0f);
        }
    }
}

// -------- init: W1 -> MFMA B-frag order; W2 -> packed f16 pairs; zero gcur ----
__global__ __launch_bounds__(256) void k_init(const float* __restrict__ W1,
                                              const float* __restrict__ W2,
                                              unsigned short* __restrict__ wf1,
                                              unsigned* __restrict__ w2p,
                                              int* __restrict__ gcur, int nbins){
    int blk = blockIdx.x, t = threadIdx.x;
    if (blk == 24){
        for (int i = t; i < nbins; i += 256) gcur[i] = 0;
        return;
    }
    int f = blk * 256 + t;
    if (f < 2048){
        int lane = f & 63;
        int ctkc = f >> 6;
        int kc = ctkc & 3, ct = ctkc >> 2;
        int col = ct * 16 + (lane & 15);
        int k0  = kc * 32 + (lane >> 4) * 8;
        unsigned short* d = wf1 + (size_t)f * 8;
        #pragma unroll
        for (int j = 0; j < 8; j++) d[j] = f2b(W1[(k0 + j) * 128 + col]);
    } else if (f < 2048 + 4096){
        int lf = f - 2048;
        int kp = lf >> 6, lane = lf & 63;
        h2 p = __builtin_amdgcn_cvt_pkrtz(W2[(2 * kp) * 64 + lane],
                                          W2[(2 * kp + 1) * 64 + lane]);
        w2p[lf] = __builtin_bit_cast(unsigned, p);
    }
}

// ---------------- GEMM1: hs1 = fp8( (x @ W1) * dinv[row] ), row-major ---------
__global__ __launch_bounds__(256) void k_gemm1(const float* __restrict__ x,
                                               const unsigned short* __restrict__ wf,
                                               const float* __restrict__ dinv,
                                               unsigned char* __restrict__ hs, int n){
    __shared__ unsigned short Wl[16384];
    __shared__ unsigned short Al[64 * 136];
    int t = threadIdx.x;
    long rowBase = (long)blockIdx.x * 64;
    {
        const uint4* s4 = (const uint4*)wf;
        uint4* d4 = (uint4*)Wl;
        #pragma unroll
        for (int i = 0; i < 8; i++) d4[t + i * 256] = s4[t + i * 256];
    }
    {
        const float4* xs = (const float4*)(x + rowBase * 128);
        #pragma unroll
        for (int k = 0; k < 8; k++){
            int i = t + k * 256;
            int r = i >> 5, c4 = (i & 31) << 2;
            float4 v = make_float4(0.f, 0.f, 0.f, 0.f);
            if (rowBase + r < n) v = xs[i];
            unsigned lo = (unsigned)f2b(v.x) | ((unsigned)f2b(v.y) << 16);
            unsigned hi = (unsigned)f2b(v.z) | ((unsigned)f2b(v.w) << 16);
            *(uint2*)&Al[r * 136 + c4] = make_uint2(lo, hi);
        }
    }
    __syncthreads();
    int w = t >> 6, lane = t & 63, lr = lane & 15, q = lane >> 4;
    floatx4 zero = {0.f, 0.f, 0.f, 0.f};
    floatx4 acc[8];
    #pragma unroll
    for (int ct = 0; ct < 8; ct++) acc[ct] = zero;
    #pragma unroll
    for (int kc = 0; kc < 4; kc++){
        bf16x8 af = *(const bf16x8*)&Al[(w * 16 + lr) * 136 + kc * 32 + q * 8];
        #pragma unroll
        for (int ct = 0; ct < 8; ct++){
            bf16x8 bf = *(const bf16x8*)&Wl[((ct * 4 + kc) * 64 + lane) * 8];
            acc[ct] = __builtin_amdgcn_mfma_f32_16x16x32_bf16(af, bf, acc[ct], 0, 0, 0);
        }
    }
    long r0 = rowBase + w * 16 + q * 4;
    #pragma unroll
    for (int r = 0; r < 4; r++){
        long row = r0 + r;
        if (row >= n) continue;
        float dv = dinv[row];
        unsigned char* orow = hs + row * 128 + lr;
        #pragma unroll
        for (int ct = 0; ct < 8; ct++) orow[ct * 16] = f2f8(acc[ct][r] * dv);
    }
}

// ---- fused agg1 + gemm2, WIDE gather: 8 fp8 rows per uint4 wave-load ---------
// lane = (g = lane>>3 row-group, q = lane&7 col-sub; cols q*16..q*16+15).
__global__ __launch_bounds__(256) void k_agg1g2(const unsigned char* __restrict__ hs,
                                                const int* __restrict__ off,
                                                const int* __restrict__ cnt,
                                                const int* __restrict__ csr,
                                                const float* __restrict__ dinv,
                                                const float* __restrict__ b1,
                                                const unsigned* __restrict__ w2p,
                                                unsigned short* __restrict__ hs2,
                                                int n, int nwaves){
    __shared__ unsigned W2l[4096];     // 16 KB packed half2 [kp][lane]
    __shared__ unsigned zp[4][64];     // packed half2 z row per wave
    int t = threadIdx.x;
    {
        const uint4* w4 = (const uint4*)w2p;
        uint4* d4 = (uint4*)W2l;
        #pragma unroll
        for (int i = 0; i < 4; i++) d4[t + i * 256] = w4[t + i * 256];
    }
    __syncthreads();
    int wband = t >> 6, lane = t & 63;
    int g = lane >> 3, q = lane & 7;
    float4 bbl = ((const float4*)b1)[q * 4 + 0];
    float4 bbh = ((const float4*)b1)[q * 4 + 1];
    float4 bbl2 = ((const float4*)b1)[q * 4 + 2];
    float4 bbh2 = ((const float4*)b1)[q * 4 + 3];
    for (int wid = blockIdx.x * 4 + wband; wid < n; wid += nwaves){
        size_t i = (size_t)wid;
        int start = off[wid], c = cnt[wid];
        float acc[16];
        #pragma unroll
        for (int k2 = 0; k2 < 16; k2++) acc[k2] = 0.f;
        int j = 0;
        for (; j + 16 <= c; j += 16){
            int r0 = csr[start + j + g];
            int r1 = csr[start + j + 8 + g];
            uint4 v0 = *(const uint4*)(hs + (size_t)r0 * 128 + q * 16);
            uint4 v1 = *(const uint4*)(hs + (size_t)r1 * 128 + q * 16);
            ACC16(v0);
            ACC16(v1);
        }
        for (; j + 8 <= c; j += 8){
            int r0 = csr[start + j + g];
            uint4 v0 = *(const uint4*)(hs + (size_t)r0 * 128 + q * 16);
            ACC16(v0);
        }
        int rem = c - j;
        if (rem > 0){
            int gg = (g < rem) ? g : 0;
            int r0 = csr[start + j + gg];
            uint4 v0 = *(const uint4*)(hs + (size_t)r0 * 128 + q * 16);
            if (g < rem){ ACC16(v0); }
        }
        // combine 8 row-groups (same cols in each group)
        #pragma unroll
        for (int k2 = 0; k2 < 16; k2++){
            acc[k2] += __shfl_xor(acc[k2], 8);
            acc[k2] += __shfl_xor(acc[k2], 16);
            acc[k2] += __shfl_xor(acc[k2], 32);
        }
        // self row (once, post-combine)
        {
            uint4 sv2 = *(const uint4*)(hs + i * 128 + q * 16);
            ACC16(sv2);
        }
        float dv = dinv[wid];
        float z[16];
        z[0]  = fmaxf(fmaf(dv, acc[0],  bbl.x), 0.f);
        z[1]  = fmaxf(fmaf(dv, acc[1],  bbl.y), 0.f);
        z[2]  = fmaxf(fmaf(dv, acc[2],  bbl.z), 0.f);
        z[3]  = fmaxf(fmaf(dv, acc[3],  bbl.w), 0.f);
        z[4]  = fmaxf(fmaf(dv, acc[4],  bbh.x), 0.f);
        z[5]  = fmaxf(fmaf(dv, acc[5],  bbh.y), 0.f);
        z[6]  = fmaxf(fmaf(dv, acc[6],  bbh.z), 0.f);
        z[7]  = fmaxf(fmaf(dv, acc[7],  bbh.w), 0.f);
        z[8]  = fmaxf(fmaf(dv, acc[8],  bbl2.x), 0.f);
        z[9]  = fmaxf(fmaf(dv, acc[9],  bbl2.y), 0.f);
        z[10] = fmaxf(fmaf(dv, acc[10], bbl2.z), 0.f);
        z[11] = fmaxf(fmaf(dv, acc[11], bbl2.w), 0.f);
        z[12] = fmaxf(fmaf(dv, acc[12], bbh2.x), 0.f);
        z[13] = fmaxf(fmaf(dv, acc[13], bbh2.y), 0.f);
        z[14] = fmaxf(fmaf(dv, acc[14], bbh2.z), 0.f);
        z[15] = fmaxf(fmaf(dv, acc[15], bbh2.w), 0.f);
        if (g == 0){
            #pragma unroll
            for (int m = 0; m < 8; m++)
                zp[wband][q * 8 + m] = __builtin_bit_cast(unsigned,
                    __builtin_amdgcn_cvt_pkrtz(z[2 * m], z[2 * m + 1]));
        }
        float acc0 = 0.f, acc1 = 0.f;
        #pragma unroll 8
        for (int kp = 0; kp < 64; kp += 2){
            h2 wa = __builtin_bit_cast(h2, W2l[kp * 64 + lane]);
            h2 wb = __builtin_bit_cast(h2, W2l[(kp + 1) * 64 + lane]);
            h2 za = __builtin_bit_cast(h2, zp[wband][kp]);
            h2 zb = __builtin_bit_cast(h2, zp[wband][kp + 1]);
            acc0 = __builtin_amdgcn_fdot2(za, wa, acc0, false);
            acc1 = __builtin_amdgcn_fdot2(zb, wb, acc1, false);
        }
        hs2[i * 64 + lane] = f2b((acc0 + acc1) * dv);
    }
}

// -------- aggregation layer 2, WIDE gather: 8 bf16 rows per uint4 wave-load ----
// lane = (g = lane>>3 row-group, q = lane&7; cols q*8..q*8+7). 1 node/wave.
__global__ __launch_bounds__(256) void k_agg2(const unsigned short* __restrict__ hs,
                                              const int* __restrict__ off,
                                              const int* __restrict__ cnt,
                                              const int* __restrict__ csr,
                                              const float* __restrict__ dinv,
                                              const float* __restrict__ b,
                                              unsigned short* __restrict__ z, int n){
    int node = (blockIdx.x * 256 + threadIdx.x) >> 6;
    int lane = threadIdx.x & 63;
    if (node >= n) return;
    int g = lane >> 3, q = lane & 7;
    size_t i = (size_t)node;
    int start = off[node], c = cnt[node];
    float4 bbl = ((const float4*)b)[q * 2];
    float4 bbh = ((const float4*)b)[q * 2 + 1];
    float acc[8];
    #pragma unroll
    for (int k2 = 0; k2 < 8; k2++) acc[k2] = 0.f;
    int j = 0;
    for (; j + 16 <= c; j += 16){
        int r0 = csr[start + j + g];
        int r1 = csr[start + j + 8 + g];
        uint4 v0 = *(const uint4*)(hs + (size_t)r0 * 64 + q * 8);
        uint4 v1 = *(const uint4*)(hs + (size_t)r1 * 64 + q * 8);
        ACC8(v0);
        ACC8(v1);
    }
    for (; j + 8 <= c; j += 8){
        int r0 = csr[start + j + g];
        uint4 v0 = *(const uint4*)(hs + (size_t)r0 * 64 + q * 8);
        ACC8(v0);
    }
    int rem = c - j;
    if (rem > 0){
        int gg = (g < rem) ? g : 0;
        int r0 = csr[start + j + gg];
        uint4 v0 = *(const uint4*)(hs + (size_t)r0 * 64 + q * 8);
        if (g < rem){ ACC8(v0); }
    }
    #pragma unroll
    for (int k2 = 0; k2 < 8; k2++){
        acc[k2] += __shfl_xor(acc[k2], 8);
        acc[k2] += __shfl_xor(acc[k2], 16);
        acc[k2] += __shfl_xor(acc[k2], 32);
    }
    {   // self row, once
        uint4 sv2 = *(const uint4*)(hs + i * 64 + q * 8);
        ACC8(sv2);
    }
    float dv = dinv[node];
    if (g == 0){
        uint4 o;
        o.x = (unsigned)f2b(fmaf(dv, acc[0], bbl.x)) | ((unsigned)f2b(fmaf(dv, acc[1], bbl.y)) << 16);
        o.y = (unsigned)f2b(fmaf(dv, acc[2], bbl.z)) | ((unsigned)f2b(fmaf(dv, acc[3], bbl.w)) << 16);
        o.z = (unsigned)f2b(fmaf(dv, acc[4], bbh.x)) | ((unsigned)f2b(fmaf(dv, acc[5], bbh.y)) << 16);
        o.w = (unsigned)f2b(fmaf(dv, acc[6], bbh.z)) | ((unsigned)f2b(fmaf(dv, acc[7], bbh.w)) << 16);
        *(uint4*)(z + i * 64 + q * 8) = o;
    }
}

// ------- decode: out[e] = dot(z2[s], z2[t]); 4 edges/wave, uint2 loads ---------
__global__ __launch_bounds__(256) void k_decode(const unsigned short* __restrict__ z,
                                                const int* __restrict__ es,
                                                const int* __restrict__ et,
                                                float* __restrict__ out, int m){
    int wv = (blockIdx.x * 256 + threadIdx.x) >> 6;
    int lane = threadIdx.x & 63;
    int e = wv * 4 + (lane >> 4);
    int ql = lane & 15;
    float p = 0.f;
    if (e < m){
        size_t s = (size_t)es[e], t2 = (size_t)et[e];
        uint2 vs = *(const uint2*)(z + s * 64 + ql * 4);
        uint2 vt = *(const uint2*)(z + t2 * 64 + ql * 4);
        p = b2f((unsigned short)vs.x) * b2f((unsigned short)vt.x)
          + b2f((unsigned short)(vs.x >> 16)) * b2f((unsigned short)(vt.x >> 16))
          + b2f((unsigned short)vs.y) * b2f((unsigned short)vt.y)
          + b2f((unsigned short)(vs.y >> 16)) * b2f((unsigned short)(vt.y >> 16));
    }
    #pragma unroll
    for (int o = 8; o > 0; o >>= 1) p += __shfl_xor(p, o);
    if (ql == 0 && e < m) out[e] = p;
}

// ---------------- launcher ----------------

extern "C" void kernel_launch(void* const* d_in, const int* in_sizes, int n_in,
                              void* d_out, int out_size, void* d_ws, size_t ws_size,
                              hipStream_t stream){
    const float* x   = (const float*)d_in[0];
    const int*   ei  = (const int*)d_in[1];
    const int*   eli = (const int*)d_in[2];
    const float* W1  = (const float*)d_in[3];
    const float* b1  = (const float*)d_in[4];
    const float* W2  = (const float*)d_in[5];
    const float* b2  = (const float*)d_in[6];
    float* out = (float*)d_out;

    int N_  = in_sizes[0] / 128;
    int E_  = in_sizes[1] / 2;
    int EL_ = in_sizes[2] / 2;
    int NBINS = (N_ + 127) >> 7;           // 782 for N=100k (must be <= 1024)
    const int EPB = 4096;
    int NBLK = (E_ + EPB - 1) / EPB;       // 391 for E=1.6M

    char* w = (char*)d_ws;
    size_t o = 0;
    auto alloc = [&](size_t bytes) -> size_t {
        size_t r = o; o += (bytes + 511) & ~(size_t)511; return r;
    };
    size_t o_cnt  = alloc((size_t)N_ * 4);
    size_t o_off  = alloc((size_t)N_ * 4);
    size_t o_dinv = alloc((size_t)N_ * 4);
    size_t o_gcur = alloc((size_t)NBINS * 4);
    size_t o_csr  = alloc((size_t)E_ * 4);
    size_t o_wf1  = alloc(16384 * 2);
    size_t o_w2p  = alloc(4096 * 4);
    size_t o_slab = alloc((size_t)NBINS * 4096 * 4);   // 12.8MB; z2 after binsort
    size_t o_hs1  = alloc((size_t)N_ * 128);           // fp8 table, 12.8MB
    size_t o_hs2  = alloc((size_t)N_ * 64 * 2);        // bf16 table, 12.8MB

    int* cnt  = (int*)(w + o_cnt);
    int* off  = (int*)(w + o_off);
    float* dinv = (float*)(w + o_dinv);
    int* gcur = (int*)(w + o_gcur);
    int* csr  = (int*)(w + o_csr);
    unsigned short* wf1 = (unsigned short*)(w + o_wf1);
    unsigned* w2p = (unsigned*)(w + o_w2p);
    unsigned* slab = (unsigned*)(w + o_slab);
    unsigned char* hs1 = (unsigned char*)(w + o_hs1);
    unsigned short* hs2 = (unsigned short*)(w + o_hs2);
    unsigned short* z2  = (unsigned short*)(w + o_slab);  // slab dead after binsort

    const int AGG1_BLOCKS = 2048;          // 8 blocks/CU (18KB LDS) -> 32 waves/CU
    int nwaves = AGG1_BLOCKS * 4;

    k_init    <<<25, 256, 0, stream>>>(W1, W2, wf1, w2p, gcur, NBINS);
    k_scatter2<<<NBLK, 256, 0, stream>>>(ei, ei + E_, gcur, slab, E_, NBINS);
    k_binsort <<<NBINS, 256, 0, stream>>>(slab, gcur, csr, cnt, off, dinv, N_, NBINS);
    k_gemm1   <<<(N_ + 63) / 64, 256, 0, stream>>>(x, wf1, dinv, hs1, N_);
    k_agg1g2  <<<AGG1_BLOCKS, 256, 0, stream>>>(hs1, off, cnt, csr, dinv, b1, w2p, hs2, N_, nwaves);
    k_agg2    <<<(N_ + 3) / 4, 256, 0, stream>>>(hs2, off, cnt, csr, dinv, b2, z2, N_);
    k_decode  <<<(EL_ + 15) / 16, 256, 0, stream>>>(z2, eli, eli + EL_, out, EL_);
}